// Round 5
// baseline (230.711 us; speedup 1.0000x reference)
//
#include <hip/hip_runtime.h>
#include <hip/hip_bf16.h>
#include <math.h>

#define T_DIM 2048
#define B_DIM 2
#define D_DIM 256
#define TC 512
#define KV_LEN 2560   // TC + T
#define HPAD 2056     // padded rows per batch for windowed gather

typedef __attribute__((ext_vector_type(8))) short bf16x8;
typedef __attribute__((ext_vector_type(4))) float f32x4;

__device__ __forceinline__ float wave_sum64(float v) {
#pragma unroll
    for (int off = 32; off > 0; off >>= 1) v += __shfl_xor(v, off, 64);
    return v;
}

__device__ __forceinline__ float rope_angle(int pos, int j) {
    float inv = powf(10000.0f, -(float)j * (1.0f / 32.0f));
    return (float)pos * inv;
}

__device__ __forceinline__ unsigned short f2bf_hi(float x) {
    __hip_bfloat16 h = __float2bfloat16(x);
    return *(unsigned short*)&h;
}

// ---------------------------------------------------------------------------
// K0: prep — split H and weights into bf16 hi/lo, build expanded transposed
// B matrices. A' = [H_hi | H_hi | H_lo],  B' = [W_hi ; W_lo ; W_hi].
// ---------------------------------------------------------------------------
__global__ __launch_bounds__(256) void k_prep(
    const float* __restrict__ H, const float* __restrict__ W_Q,
    const float* __restrict__ W_KV, const float* __restrict__ W_DQ,
    const float* __restrict__ Wc_comp, const float* __restrict__ Wc_idx,
    unsigned short* __restrict__ Hp_hi, unsigned short* __restrict__ Hp_lo,
    unsigned short* __restrict__ Bpt, unsigned short* __restrict__ Bct)
{
    int gtid = blockIdx.x * 256 + threadIdx.x;
    int gstride = gridDim.x * 256;

    // H split with zero pad rows [2048, HPAD)
    for (int i = gtid; i < B_DIM * HPAD * 256; i += gstride) {
        int b = i / (HPAD * 256);
        int rem = i - b * (HPAD * 256);
        int row = rem >> 8;
        int col = rem & 255;
        float x = (row < T_DIM) ? H[((size_t)b * T_DIM + row) * 256 + col] : 0.f;
        unsigned short hi = f2bf_hi(x);
        __hip_bfloat16 hb = *(__hip_bfloat16*)&hi;
        float hif = __bfloat162float(hb);
        unsigned short lo = f2bf_hi(x - hif);
        Hp_hi[i] = hi;
        Hp_lo[i] = lo;
    }

    // Bpt[n][k'] : n in [0,384), k' in [0,768)
    for (int i = gtid; i < 384 * 768; i += gstride) {
        int n = i / 768;
        int kp = i - n * 768;
        int k = kp & 255;
        float w;
        if (n < 256)      w = W_Q[(size_t)k * 256 + n];
        else if (n < 320) w = W_KV[(size_t)k * 64 + (n - 256)];
        else              w = W_DQ[(size_t)k * 64 + (n - 320)];
        unsigned short hi = f2bf_hi(w);
        __hip_bfloat16 hb = *(__hip_bfloat16*)&hi;
        unsigned short lo = f2bf_hi(w - __bfloat162float(hb));
        Bpt[i] = (kp >= 256 && kp < 512) ? lo : hi;
    }

    // Bct[n][k'] : n in [0,96), k' in [0,6144)
    for (int i = gtid; i < 96 * 6144; i += gstride) {
        int n = i / 6144;
        int kp = i - n * 6144;
        int k = kp & 2047;
        float w = (n < 64) ? Wc_comp[(size_t)k * 64 + n]
                           : Wc_idx[(size_t)k * 32 + (n - 64)];
        unsigned short hi = f2bf_hi(w);
        __hip_bfloat16 hb = *(__hip_bfloat16*)&hi;
        unsigned short lo = f2bf_hi(w - __bfloat162float(hb));
        Bct[i] = (kp >= 2048 && kp < 4096) ? lo : hi;
    }
}

// ---------------------------------------------------------------------------
// K1: MFMA GEMMs, all-global (no LDS, no barriers).
// blocks [0,64): proj — block tile M=64 tokens x N=384; wave w cols w*96..+95.
// blocks [64,80): compress — block tile M=64 comp tokens x N=96; waves split
// K (1536 each), partials to Prec_part[w].
// Fragment layouts (mfma_f32_16x16x32_bf16):
//   A: lane holds A[m=lane&15][k=8*(lane>>4)+j]  (bf16x8, 16B contiguous)
//   B: lane holds B[k=8*(lane>>4)+j][n=lane&15]  -> load from transposed Bt[n][k]
//   C/D: col=lane&15, row=4*(lane>>4)+reg
// ---------------------------------------------------------------------------
__global__ __launch_bounds__(256) void k_mfma(
    const unsigned short* __restrict__ Hp_hi, const unsigned short* __restrict__ Hp_lo,
    const unsigned short* __restrict__ Bpt, const unsigned short* __restrict__ Bct,
    float* __restrict__ Pre, float* __restrict__ Prec_part)
{
    int tid = threadIdx.x;
    int w = tid >> 6;
    int lane = tid & 63;
    int mrow = lane & 15;
    int q = lane >> 4;

    if (blockIdx.x < 64) {
        // ---------------- proj ----------------
        int bt0 = blockIdx.x * 64;
        int b = bt0 >> 11;
        int t0 = bt0 & 2047;
        int n0 = w * 96;

        f32x4 acc[4][6];
#pragma unroll
        for (int mt = 0; mt < 4; ++mt)
#pragma unroll
            for (int nt = 0; nt < 6; ++nt) acc[mt][nt] = (f32x4){0.f, 0.f, 0.f, 0.f};

        const size_t abase = (size_t)(b * HPAD + t0 + mrow) * 256;

        for (int ks = 0; ks < 24; ++ks) {
            int seg = ks >> 3;
            int kk = 32 * (ks & 7) + 8 * q;
            const unsigned short* Asrc = (seg < 2 ? Hp_hi : Hp_lo);
            int kp = 32 * ks + 8 * q;

            bf16x8 af[4];
#pragma unroll
            for (int mt = 0; mt < 4; ++mt)
                af[mt] = *(const bf16x8*)(Asrc + abase + (size_t)(16 * mt) * 256 + kk);
            bf16x8 bfb[6];
#pragma unroll
            for (int nt = 0; nt < 6; ++nt)
                bfb[nt] = *(const bf16x8*)(Bpt + (size_t)(n0 + 16 * nt + mrow) * 768 + kp);
#pragma unroll
            for (int mt = 0; mt < 4; ++mt)
#pragma unroll
                for (int nt = 0; nt < 6; ++nt)
                    acc[mt][nt] = __builtin_amdgcn_mfma_f32_16x16x32_bf16(
                        af[mt], bfb[nt], acc[mt][nt], 0, 0, 0);
        }

#pragma unroll
        for (int mt = 0; mt < 4; ++mt)
#pragma unroll
            for (int nt = 0; nt < 6; ++nt)
#pragma unroll
                for (int reg = 0; reg < 4; ++reg)
                    Pre[(size_t)(bt0 + 16 * mt + 4 * q + reg) * 384 + n0 + 16 * nt + mrow] =
                        acc[mt][nt][reg];
    } else {
        // ---------------- compress ----------------
        int cid = blockIdx.x - 64;
        int m0 = cid * 64;
        int b = m0 >> 9;
        int s0 = m0 & 511;
        int kw = w * 1536;

        f32x4 acc[4][6];
#pragma unroll
        for (int mt = 0; mt < 4; ++mt)
#pragma unroll
            for (int nt = 0; nt < 6; ++nt) acc[mt][nt] = (f32x4){0.f, 0.f, 0.f, 0.f};

        for (int ks = 0; ks < 48; ++ks) {
            int kp = kw + 32 * ks + 8 * q;
            int seg = kp >> 11;
            int kk = kp & 2047;
            int row_off = kk >> 8;
            int kcol = kk & 255;
            const unsigned short* Asrc = (seg < 2 ? Hp_hi : Hp_lo);

            bf16x8 af[4];
#pragma unroll
            for (int mt = 0; mt < 4; ++mt) {
                int m = s0 + 16 * mt + mrow;
                af[mt] = *(const bf16x8*)(Asrc + (size_t)(b * HPAD + 4 * m + row_off) * 256 + kcol);
            }
            bf16x8 bfb[6];
#pragma unroll
            for (int nt = 0; nt < 6; ++nt)
                bfb[nt] = *(const bf16x8*)(Bct + (size_t)(16 * nt + mrow) * 6144 + kp);
#pragma unroll
            for (int mt = 0; mt < 4; ++mt)
#pragma unroll
                for (int nt = 0; nt < 6; ++nt)
                    acc[mt][nt] = __builtin_amdgcn_mfma_f32_16x16x32_bf16(
                        af[mt], bfb[nt], acc[mt][nt], 0, 0, 0);
        }

        float* dst = Prec_part + (size_t)w * (1024 * 96);
#pragma unroll
        for (int mt = 0; mt < 4; ++mt)
#pragma unroll
            for (int nt = 0; nt < 6; ++nt)
#pragma unroll
                for (int reg = 0; reg < 4; ++reg)
                    dst[(size_t)(m0 + 16 * mt + 4 * q + reg) * 96 + 16 * nt + mrow] =
                        acc[mt][nt][reg];
    }
}

// ---------------------------------------------------------------------------
// K2a: proj epilogue — RMS/RoPE on Q and sliding KV, QI/Wiw from H_dc.
// 4 tokens/block, wave per token (verified R3 logic, reading Pre).
// ---------------------------------------------------------------------------
__global__ __launch_bounds__(256) void k_epi_proj(
    const float* __restrict__ Pre, const float* __restrict__ W_IUQ,
    const float* __restrict__ W_w, const float* __restrict__ g_q,
    const float* __restrict__ g_k, const float* __restrict__ g_v,
    float* __restrict__ QI, float* __restrict__ Wiw, float* __restrict__ Qr,
    float* __restrict__ Kbuf, float* __restrict__ Vbuf)
{
    int tid = threadIdx.x;
    int wv = tid >> 6;
    int lane = tid & 63;
    int bt = blockIdx.x * 4 + wv;
    int b = bt >> 11;
    int t = bt & 2047;

    __shared__ float sWI[8192];
    __shared__ float sWw[256];
    __shared__ float sHdc[4][64];

    for (int i = tid * 4; i < 8192; i += 1024)
        *(float4*)&sWI[i] = *(const float4*)(W_IUQ + i);
    if (tid < 64) ((float4*)sWw)[tid] = ((const float4*)W_w)[tid];

    const float* pr = Pre + (size_t)bt * 384;
    sHdc[wv][lane] = pr[320 + lane];
    __syncthreads();

    int j = lane & 31;
    float s_t, c_t;
    sincosf(rope_angle(t, j), &s_t, &c_t);

#pragma unroll
    for (int r = 0; r < 4; ++r) {
        float qv = pr[r * 64 + lane];
        float ss = wave_sum64(qv * qv);
        float sc = rsqrtf(ss * (1.0f / 64.0f) + 1e-6f);
        float qq = qv * sc * g_q[r * 64 + lane];
        float prt = __shfl_xor(qq, 32, 64);
        float o = (lane < 32) ? fmaf(qq, c_t, -prt * s_t)
                              : fmaf(prt, s_t, qq * c_t);
        Qr[(size_t)bt * 256 + r * 64 + lane] = o;
    }
    {
        float kvv = pr[256 + lane];
        float ss = wave_sum64(kvv * kvv);
        float sc = rsqrtf(ss * (1.0f / 64.0f) + 1e-6f);
        float kk = kvv * sc * g_k[lane];
        float vv = kvv * sc * g_v[lane];
        int pos = TC + t;
        float s_p, c_p;
        sincosf(rope_angle(pos, j), &s_p, &c_p);
        float pk = __shfl_xor(kk, 32, 64);
        float pv = __shfl_xor(vv, 32, 64);
        float ko = (lane < 32) ? fmaf(kk, c_p, -pk * s_p) : fmaf(pk, s_p, kk * c_p);
        float vo = (lane < 32) ? fmaf(vv, c_p, -pv * s_p) : fmaf(pv, s_p, vv * c_p);
        size_t off = ((size_t)b * KV_LEN + pos) * 64 + lane;
        Kbuf[off] = ko;
        Vbuf[off] = vo;
    }
    {
        float a0 = 0.f, a1 = 0.f;
#pragma unroll 8
        for (int jj = 0; jj < 64; ++jj) {
            float hv = sHdc[wv][jj];
            a0 = fmaf(hv, sWI[jj * 128 + lane], a0);
            a1 = fmaf(hv, sWI[jj * 128 + 64 + lane], a1);
        }
        QI[(size_t)bt * 128 + lane] = a0;
        QI[(size_t)bt * 128 + 64 + lane] = a1;
        if (lane < 4) {
            float aw = 0.f;
            for (int jj = 0; jj < 64; ++jj)
                aw = fmaf(sHdc[wv][jj], sWw[jj * 4 + lane], aw);
            Wiw[(size_t)bt * 4 + lane] = aw;
        }
    }
}

// ---------------------------------------------------------------------------
// K2b: compress epilogue — sum 4 K-split partials, RMS/RoPE -> Kb/Vb, KI.
// 4 comp tokens/block, wave per token.
// ---------------------------------------------------------------------------
__global__ __launch_bounds__(256) void k_epi_comp(
    const float* __restrict__ Prec_part, const float* __restrict__ g_k,
    const float* __restrict__ g_v,
    float* __restrict__ KIbuf, float* __restrict__ Kbuf, float* __restrict__ Vbuf)
{
    int tid = threadIdx.x;
    int wv = tid >> 6;
    int lane = tid & 63;
    int sg = blockIdx.x * 4 + wv;
    int b = sg >> 9;
    int s = sg & 511;

    const float* p0 = Prec_part + (size_t)sg * 96;
    float kvv = p0[lane] + p0[98304 + lane] + p0[2 * 98304 + lane] + p0[3 * 98304 + lane];

    float ss = wave_sum64(kvv * kvv);
    float sc = rsqrtf(ss * (1.0f / 64.0f) + 1e-6f);
    float kk = kvv * sc * g_k[lane];
    float vv = kvv * sc * g_v[lane];
    int j = lane & 31;
    float sa, ca;
    sincosf(rope_angle(s, j), &sa, &ca);
    float pk = __shfl_xor(kk, 32, 64);
    float pv = __shfl_xor(vv, 32, 64);
    float ko = (lane < 32) ? fmaf(kk, ca, -pk * sa) : fmaf(pk, sa, kk * ca);
    float vo = (lane < 32) ? fmaf(vv, ca, -pv * sa) : fmaf(pv, sa, vv * ca);
    size_t off = ((size_t)b * KV_LEN + s) * 64 + lane;
    Kbuf[off] = ko;
    Vbuf[off] = vo;

    if (lane < 32) {
        float a = p0[64 + lane] + p0[98304 + 64 + lane] +
                  p0[2 * 98304 + 64 + lane] + p0[3 * 98304 + 64 + lane];
        KIbuf[((size_t)b * TC + s) * 32 + lane] = a;
    }
}

// ---------------------------------------------------------------------------
// K3: index scores + exact top-8 (unchanged, verified).
// ---------------------------------------------------------------------------
__global__ __launch_bounds__(256) void k_score_topk(
    const float* __restrict__ QI, const float* __restrict__ Wiw,
    const float* __restrict__ KIbuf, int* __restrict__ topk)
{
    int tid = threadIdx.x;
    int wv = tid >> 6;
    int lane = tid & 63;
    int bt0 = blockIdx.x * 4;
    int bt = bt0 + wv;
    int b = bt >> 11;
    int t = bt & 2047;

    __shared__ float sQ[4][128];
    __shared__ float sw[4][4];
    __shared__ float sKI[64 * 33];

    sQ[wv][lane] = QI[(size_t)bt * 128 + lane];
    sQ[wv][64 + lane] = QI[(size_t)bt * 128 + 64 + lane];
    if (lane < 4) sw[wv][lane] = Wiw[(size_t)bt * 4 + lane];

    const float* KIb = KIbuf + (size_t)b * TC * 32;
    int smax = t >> 2;
    int smax_blk = ((bt0 + 3) & 2047) >> 2;

    float vals[8];
#pragma unroll
    for (int r = 0; r < 8; ++r) vals[r] = -INFINITY;

    for (int r = 0; r < 8; ++r) {
        if (r * 64 > smax_blk) break;
        __syncthreads();
        for (int i = tid; i < 512; i += 256) {
            int row = i >> 3;
            int cseg = (i & 7) * 4;
            float4 v = *(const float4*)(KIb + (size_t)(r * 64 + row) * 32 + cseg);
            float* dst = &sKI[row * 33 + cseg];
            dst[0] = v.x; dst[1] = v.y; dst[2] = v.z; dst[3] = v.w;
        }
        __syncthreads();

        int s = r * 64 + lane;
        if (s <= smax) {
            float dd0 = 0.f, dd1 = 0.f, dd2 = 0.f, dd3 = 0.f;
#pragma unroll
            for (int c = 0; c < 32; ++c) {
                float kv = sKI[lane * 33 + c];
                dd0 = fmaf(sQ[wv][c], kv, dd0);
                dd1 = fmaf(sQ[wv][32 + c], kv, dd1);
                dd2 = fmaf(sQ[wv][64 + c], kv, dd2);
                dd3 = fmaf(sQ[wv][96 + c], kv, dd3);
            }
            vals[r] = sw[wv][0] * fmaxf(dd0, 0.f) + sw[wv][1] * fmaxf(dd1, 0.f) +
                      sw[wv][2] * fmaxf(dd2, 0.f) + sw[wv][3] * fmaxf(dd3, 0.f);
        }
    }

    unsigned consumed = 0u;
    for (int k2 = 0; k2 < 8; ++k2) {
        float bv = -INFINITY;
        int bi = 0x7fffffff;
#pragma unroll
        for (int r = 0; r < 8; ++r) {
            if (!(consumed & (1u << r))) {
                int s = lane + 64 * r;
                float v = vals[r];
                if (v > bv || (v == bv && s < bi)) { bv = v; bi = s; }
            }
        }
#pragma unroll
        for (int off = 1; off < 64; off <<= 1) {
            float ov = __shfl_xor(bv, off, 64);
            int oi = __shfl_xor(bi, off, 64);
            if (ov > bv || (ov == bv && oi < bi)) { bv = ov; bi = oi; }
        }
        if ((bi & 63) == lane) consumed |= 1u << (bi >> 6);
        if (lane == 0) topk[(size_t)bt * 8 + k2] = bi;
    }
}

// ---------------------------------------------------------------------------
// K4: sparse attention + gates + out (unchanged, verified).
// ---------------------------------------------------------------------------
__global__ __launch_bounds__(1024) void k_attn_out(
    const float* __restrict__ Qr, const float* __restrict__ Kbuf,
    const float* __restrict__ Vbuf, const int* __restrict__ topk,
    const float* __restrict__ Wg0, const float* __restrict__ bg0,
    const float* __restrict__ Wg1, const float* __restrict__ bg1,
    const float* __restrict__ Wout, const float* __restrict__ bout,
    float* __restrict__ out)
{
    int tid = threadIdx.x;
    int lt = tid >> 8;
    int t256 = tid & 255;
    int h = t256 >> 6;
    int lane = tid & 63;
    int bt = blockIdx.x * 4 + lt;
    int b = bt >> 11;
    int t = bt & 2047;

    __shared__ float sKV[4][48 * 65];
    __shared__ float sQ[4][256];
    __shared__ int sPos[4][24];
    __shared__ float sP[4][4][24];
    __shared__ float sO[4][256];
    __shared__ float sPall[4][128];

    sQ[lt][t256] = Qr[(size_t)bt * 256 + t256];
    if (t256 < 8) {
        sPos[lt][t256] = topk[(size_t)bt * 8 + t256];
    } else if (t256 < 24) {
        int rel = t256 - 8;
        int sp = t - rel;
        sPos[lt][t256] = (sp >= 0) ? (TC + sp) : -1;
    }
    __syncthreads();

    for (int i = t256; i < 768; i += 256) {
        int row = i >> 4;
        int seg = (i & 15) << 2;
        int key = (row < 24) ? row : row - 24;
        int pos = sPos[lt][key];
        if (pos >= 0) {
            const float* src = ((row < 24) ? Kbuf : Vbuf) +
                               ((size_t)b * KV_LEN + pos) * 64 + seg;
            float4 v = *(const float4*)src;
            float* dst = &sKV[lt][row * 65 + seg];
            dst[0] = v.x; dst[1] = v.y; dst[2] = v.z; dst[3] = v.w;
        }
    }
    __syncthreads();

    float scv = -INFINITY;
    if (lane < 24) {
        int pos = sPos[lt][lane];
        if (pos >= 0) {
            float dd = 0.f;
#pragma unroll
            for (int c = 0; c < 64; ++c)
                dd = fmaf(sQ[lt][h * 64 + c], sKV[lt][lane * 65 + c], dd);
            scv = dd * 0.125f;
        }
    }
    float m = scv;
#pragma unroll
    for (int off = 1; off < 64; off <<= 1) m = fmaxf(m, __shfl_xor(m, off, 64));
    float p = expf(scv - m);
    if (scv == -INFINITY) p = 0.f;
    float l = p;
#pragma unroll
    for (int off = 1; off < 64; off <<= 1) l += __shfl_xor(l, off, 64);
    p /= l;
    if (lane < 24) sP[lt][h][lane] = p;

    float o = 0.f;
#pragma unroll
    for (int j2 = 0; j2 < 24; ++j2) {
        int pos = sPos[lt][j2];
        if (pos >= 0)
            o = fmaf(sP[lt][h][j2], sKV[lt][(24 + j2) * 65 + lane], o);
    }

    int j = lane & 31;
    float sa, ca;
    sincosf(rope_angle(t, j), &sa, &ca);
    float prt = __shfl_xor(o, 32, 64);
    float oo = (lane < 32) ? fmaf(o, ca, prt * sa) : fmaf(-prt, sa, o * ca);
    sO[lt][h * 64 + lane] = oo;
    __syncthreads();

    if (t256 < 128) {
        float a;
        if (t256 < 64) {
            a = bg0[t256];
            for (int c = 0; c < 128; ++c) a = fmaf(sO[lt][c], Wg0[c * 64 + t256], a);
        } else {
            int i = t256 - 64;
            a = bg1[i];
            for (int c = 0; c < 128; ++c) a = fmaf(sO[lt][128 + c], Wg1[c * 64 + i], a);
        }
        sPall[lt][t256] = a;
    }
    __syncthreads();

    float a = bout[t256];
    for (int i = 0; i < 128; ++i) a = fmaf(sPall[lt][i], Wout[i * 256 + t256], a);
    out[(size_t)bt * 256 + t256] = a;
}

// ---------------------------------------------------------------------------
extern "C" void kernel_launch(void* const* d_in, const int* in_sizes, int n_in,
                              void* d_out, int out_size, void* d_ws, size_t ws_size,
                              hipStream_t stream) {
    const float* H       = (const float*)d_in[0];
    const float* Wc_comp = (const float*)d_in[1];
    const float* Wc_idx  = (const float*)d_in[2];
    const float* W_DQ    = (const float*)d_in[3];
    const float* W_IUQ   = (const float*)d_in[4];
    const float* W_w     = (const float*)d_in[5];
    const float* W_Q     = (const float*)d_in[6];
    const float* W_KV    = (const float*)d_in[7];
    const float* g_q     = (const float*)d_in[8];
    const float* g_k     = (const float*)d_in[9];
    const float* g_v     = (const float*)d_in[10];
    const float* Wg0     = (const float*)d_in[11];
    const float* bg0     = (const float*)d_in[12];
    const float* Wg1     = (const float*)d_in[13];
    const float* bg1     = (const float*)d_in[14];
    const float* Wout    = (const float*)d_in[15];
    const float* bout    = (const float*)d_in[16];

    float* ws  = (float*)d_ws;
    float* QI   = ws;                     // 524288
    float* Qr   = ws + 524288;            // 1048576
    float* Wiw  = ws + 1572864;           // 16384
    float* KI   = ws + 1589248;           // 32768
    float* Kb   = ws + 1622016;           // 327680
    float* Vb   = ws + 1949696;           // 327680
    int*   topkb = (int*)(ws + 2277376);  // 32768
    float* Pre  = ws + 2310144;           // 4096*384 = 1572864
    float* Prec = ws + 3883008;           // 4*1024*96 = 393216
    unsigned short* Hp_hi = (unsigned short*)(ws + 4276224); // 2*2056*256 ush
    unsigned short* Hp_lo = (unsigned short*)(ws + 4802560);
    unsigned short* Bpt   = (unsigned short*)(ws + 5328896); // 384*768 ush
    unsigned short* Bct   = (unsigned short*)(ws + 5476352); // 96*6144 ush

    float* outp = (float*)d_out;

    hipLaunchKernelGGL(k_prep, dim3(512), dim3(256), 0, stream,
                       H, W_Q, W_KV, W_DQ, Wc_comp, Wc_idx, Hp_hi, Hp_lo, Bpt, Bct);
    hipLaunchKernelGGL(k_mfma, dim3(80), dim3(256), 0, stream,
                       Hp_hi, Hp_lo, Bpt, Bct, Pre, Prec);
    hipLaunchKernelGGL(k_epi_proj, dim3(1024), dim3(256), 0, stream,
                       Pre, W_IUQ, W_w, g_q, g_k, g_v, QI, Wiw, Qr, Kb, Vb);
    hipLaunchKernelGGL(k_epi_comp, dim3(256), dim3(256), 0, stream,
                       Prec, g_k, g_v, KI, Kb, Vb);
    hipLaunchKernelGGL(k_score_topk, dim3((B_DIM * T_DIM) / 4), dim3(256), 0, stream,
                       QI, Wiw, KI, topkb);
    hipLaunchKernelGGL(k_attn_out, dim3((B_DIM * T_DIM) / 4), dim3(1024), 0, stream,
                       Qr, Kb, Vb, topkb, Wg0, bg0, Wg1, bg1, Wout, bout, outp);
}

// Round 6
// 193.110 us; speedup vs baseline: 1.1947x; 1.1947x over previous
//
#include <hip/hip_runtime.h>
#include <hip/hip_bf16.h>
#include <math.h>

#define T_DIM 2048
#define B_DIM 2
#define D_DIM 256
#define TC 512
#define KV_LEN 2560   // TC + T

typedef __attribute__((ext_vector_type(8))) short bf16x8;
typedef __attribute__((ext_vector_type(4))) float f32x4;
typedef unsigned short ush;

__device__ __forceinline__ float wave_sum64(float v) {
#pragma unroll
    for (int off = 32; off > 0; off >>= 1) v += __shfl_xor(v, off, 64);
    return v;
}

__device__ __forceinline__ float rope_angle(int pos, int j) {
    float inv = powf(10000.0f, -(float)j * (1.0f / 32.0f));
    return (float)pos * inv;
}

// ---------------------------------------------------------------------------
// K0: prep — build MFMA-fragment-linear bf16 hi/lo tiles.
// Layout: buf[(tile16*NCHUNK + c)*512 + lane*8 + j]
//   value = part(H_or_W[row = tile16*16 + (lane&15)][k = kbase(c) + (lane>>4)*8 + j])
//   chunks [0,NCHUNK/2) = hi part, [NCHUNK/2, NCHUNK) = lo part.
// Ap: proj A (4096 rows x 256 k)            : 256 tiles x 16 chunks
// Ac: compress A (1024 wins x 2048 k2)      : 64 tiles x 128 chunks (zero-pad tail)
// Bp: proj B^T ([W_Q|W_KV|W_DQ], 384 x 256) : 24 tiles x 16 chunks
// Bc: comp B^T ([Wc_comp|Wc_idx], 96 x 2048): 6 tiles x 128 chunks
// ---------------------------------------------------------------------------
__global__ __launch_bounds__(256) void k_prep(
    const float* __restrict__ H, const float* __restrict__ W_Q,
    const float* __restrict__ W_KV, const float* __restrict__ W_DQ,
    const float* __restrict__ Wc_comp, const float* __restrict__ Wc_idx,
    ush* __restrict__ Ap, ush* __restrict__ Ac,
    ush* __restrict__ Bp, ush* __restrict__ Bc)
{
    int gid = blockIdx.x * 256 + threadIdx.x;
    float vals[8];
    ush* dst;
    bool lo_part;

    if (gid < 262144) {
        // ---- Ap ----
        int tile = gid >> 10;
        int c = (gid >> 6) & 15;
        int l = gid & 63;
        int bt = tile * 16 + (l & 15);
        int kb = (c & 7) * 32 + (l >> 4) * 8;
        const float* src = H + (size_t)bt * 256 + kb;
#pragma unroll
        for (int j = 0; j < 8; ++j) vals[j] = src[j];
        lo_part = (c >= 8);
        dst = Ap + (size_t)gid * 8;
    } else if (gid < 786432) {
        // ---- Ac ----
        int g = gid - 262144;
        int tile = g >> 13;
        int c = (g >> 6) & 127;
        int l = g & 63;
        int m = tile * 16 + (l & 15);
        int s = m & 511;
        int b = m >> 9;
        int k2b = (c & 63) * 32 + (l >> 4) * 8;
        int r4 = 4 * s + (k2b >> 8);
        int col = k2b & 255;
        if (r4 < T_DIM) {
            const float* src = H + ((size_t)b * T_DIM + r4) * 256 + col;
#pragma unroll
            for (int j = 0; j < 8; ++j) vals[j] = src[j];
        } else {
#pragma unroll
            for (int j = 0; j < 8; ++j) vals[j] = 0.f;
        }
        lo_part = (c >= 64);
        dst = Ac + (size_t)g * 8;
    } else if (gid < 811008) {
        // ---- Bp ----
        int g = gid - 786432;
        int tile = g >> 10;
        int c = (g >> 6) & 15;
        int l = g & 63;
        int n = tile * 16 + (l & 15);
        int kb = (c & 7) * 32 + (l >> 4) * 8;
#pragma unroll
        for (int j = 0; j < 8; ++j) {
            int k = kb + j;
            float w;
            if (n < 256)      w = W_Q[(size_t)k * 256 + n];
            else if (n < 320) w = W_KV[(size_t)k * 64 + (n - 256)];
            else              w = W_DQ[(size_t)k * 64 + (n - 320)];
            vals[j] = w;
        }
        lo_part = (c >= 8);
        dst = Bp + (size_t)g * 8;
    } else if (gid < 860160) {
        // ---- Bc ----
        int g = gid - 811008;
        int tile = g >> 13;
        int c = (g >> 6) & 127;
        int l = g & 63;
        int n = tile * 16 + (l & 15);
        int k2b = (c & 63) * 32 + (l >> 4) * 8;
#pragma unroll
        for (int j = 0; j < 8; ++j) {
            int k = k2b + j;
            vals[j] = (n < 64) ? Wc_comp[(size_t)k * 64 + n]
                               : Wc_idx[(size_t)k * 32 + (n - 64)];
        }
        lo_part = (c >= 64);
        dst = Bc + (size_t)g * 8;
    } else {
        return;
    }

    bf16x8 out;
#pragma unroll
    for (int j = 0; j < 8; ++j) {
        float x = vals[j];
        __hip_bfloat16 hb = __float2bfloat16(x);
        if (!lo_part) {
            out[j] = *(short*)&hb;
        } else {
            float hif = __bfloat162float(hb);
            __hip_bfloat16 lb = __float2bfloat16(x - hif);
            out[j] = *(short*)&lb;
        }
    }
    *(bf16x8*)dst = out;
}

// ---------------------------------------------------------------------------
// K1: MFMA GEMMs. One wave per block (64 thr), 640 blocks.
// blocks [0,512): proj — wave tile M=32 x N=96, full K. p = mtile32*4 + nq.
// blocks [512,640): compress — wave tile M=32 x N=96, K-quarter q4 of the
// 2048-wide k2 range; partials to Prec_part[q4].
// Per chunk c: acc += Ahi*Bhi + Ahi*Blo + Alo*Bhi  (exact fp32 split).
// All fragment loads are lane-linear 1KB coalesced reads.
// C/D layout: col=lane&15, row=4*(lane>>4)+reg (verified R5).
// ---------------------------------------------------------------------------
__global__ __launch_bounds__(64) void k_mfma(
    const ush* __restrict__ Ap, const ush* __restrict__ Ac,
    const ush* __restrict__ Bp, const ush* __restrict__ Bc,
    float* __restrict__ Pre, float* __restrict__ Prec_part)
{
    int lane = threadIdx.x;
    int mrow = lane & 15;
    int q = lane >> 4;

    f32x4 acc[2][6];
#pragma unroll
    for (int mt = 0; mt < 2; ++mt)
#pragma unroll
        for (int nt = 0; nt < 6; ++nt) acc[mt][nt] = (f32x4){0.f, 0.f, 0.f, 0.f};

    if (blockIdx.x < 512) {
        // ---------------- proj ----------------
        int p = blockIdx.x;
        int m0 = (p >> 2) * 32;
        int n0 = (p & 3) * 96;
        int at0 = (m0 >> 4) * 16;        // tile16 base * NCHUNK(16)
        int bt0n = (n0 >> 4) * 16;

        for (int c = 0; c < 8; ++c) {
            bf16x8 ahi[2], alo[2], bhi[6], blo[6];
#pragma unroll
            for (int mt = 0; mt < 2; ++mt) {
                ahi[mt] = *(const bf16x8*)(Ap + (size_t)((at0 + mt * 16) + c) * 512 + lane * 8);
                alo[mt] = *(const bf16x8*)(Ap + (size_t)((at0 + mt * 16) + 8 + c) * 512 + lane * 8);
            }
#pragma unroll
            for (int nt = 0; nt < 6; ++nt) {
                bhi[nt] = *(const bf16x8*)(Bp + (size_t)((bt0n + nt * 16) + c) * 512 + lane * 8);
                blo[nt] = *(const bf16x8*)(Bp + (size_t)((bt0n + nt * 16) + 8 + c) * 512 + lane * 8);
            }
#pragma unroll
            for (int mt = 0; mt < 2; ++mt)
#pragma unroll
                for (int nt = 0; nt < 6; ++nt) {
                    acc[mt][nt] = __builtin_amdgcn_mfma_f32_16x16x32_bf16(ahi[mt], bhi[nt], acc[mt][nt], 0, 0, 0);
                    acc[mt][nt] = __builtin_amdgcn_mfma_f32_16x16x32_bf16(ahi[mt], blo[nt], acc[mt][nt], 0, 0, 0);
                    acc[mt][nt] = __builtin_amdgcn_mfma_f32_16x16x32_bf16(alo[mt], bhi[nt], acc[mt][nt], 0, 0, 0);
                }
        }

#pragma unroll
        for (int mt = 0; mt < 2; ++mt)
#pragma unroll
            for (int nt = 0; nt < 6; ++nt)
#pragma unroll
                for (int reg = 0; reg < 4; ++reg)
                    Pre[(size_t)(m0 + 16 * mt + 4 * q + reg) * 384 + n0 + 16 * nt + mrow] =
                        acc[mt][nt][reg];
    } else {
        // ---------------- compress ----------------
        int cb = blockIdx.x - 512;
        int m0 = (cb >> 2) * 32;
        int q4 = cb & 3;
        int at0 = (m0 >> 4) * 128;

        for (int cl = 0; cl < 16; ++cl) {
            int c = q4 * 16 + cl;
            bf16x8 ahi[2], alo[2], bhi[6], blo[6];
#pragma unroll
            for (int mt = 0; mt < 2; ++mt) {
                ahi[mt] = *(const bf16x8*)(Ac + (size_t)((at0 + mt * 128) + c) * 512 + lane * 8);
                alo[mt] = *(const bf16x8*)(Ac + (size_t)((at0 + mt * 128) + 64 + c) * 512 + lane * 8);
            }
#pragma unroll
            for (int nt = 0; nt < 6; ++nt) {
                bhi[nt] = *(const bf16x8*)(Bc + (size_t)(nt * 128 + c) * 512 + lane * 8);
                blo[nt] = *(const bf16x8*)(Bc + (size_t)(nt * 128 + 64 + c) * 512 + lane * 8);
            }
#pragma unroll
            for (int mt = 0; mt < 2; ++mt)
#pragma unroll
                for (int nt = 0; nt < 6; ++nt) {
                    acc[mt][nt] = __builtin_amdgcn_mfma_f32_16x16x32_bf16(ahi[mt], bhi[nt], acc[mt][nt], 0, 0, 0);
                    acc[mt][nt] = __builtin_amdgcn_mfma_f32_16x16x32_bf16(ahi[mt], blo[nt], acc[mt][nt], 0, 0, 0);
                    acc[mt][nt] = __builtin_amdgcn_mfma_f32_16x16x32_bf16(alo[mt], bhi[nt], acc[mt][nt], 0, 0, 0);
                }
        }

        float* dst = Prec_part + (size_t)q4 * (1024 * 96);
#pragma unroll
        for (int mt = 0; mt < 2; ++mt)
#pragma unroll
            for (int nt = 0; nt < 6; ++nt)
#pragma unroll
                for (int reg = 0; reg < 4; ++reg)
                    dst[(size_t)(m0 + 16 * mt + 4 * q + reg) * 96 + 16 * nt + mrow] =
                        acc[mt][nt][reg];
    }
}

// ---------------------------------------------------------------------------
// K2a: proj epilogue — RMS/RoPE on Q and sliding KV, QI/Wiw from H_dc.
// 4 tokens/block, wave per token (verified).
// ---------------------------------------------------------------------------
__global__ __launch_bounds__(256) void k_epi_proj(
    const float* __restrict__ Pre, const float* __restrict__ W_IUQ,
    const float* __restrict__ W_w, const float* __restrict__ g_q,
    const float* __restrict__ g_k, const float* __restrict__ g_v,
    float* __restrict__ QI, float* __restrict__ Wiw, float* __restrict__ Qr,
    float* __restrict__ Kbuf, float* __restrict__ Vbuf)
{
    int tid = threadIdx.x;
    int wv = tid >> 6;
    int lane = tid & 63;
    int bt = blockIdx.x * 4 + wv;
    int b = bt >> 11;
    int t = bt & 2047;

    __shared__ float sWI[8192];
    __shared__ float sWw[256];
    __shared__ float sHdc[4][64];

    for (int i = tid * 4; i < 8192; i += 1024)
        *(float4*)&sWI[i] = *(const float4*)(W_IUQ + i);
    if (tid < 64) ((float4*)sWw)[tid] = ((const float4*)W_w)[tid];

    const float* pr = Pre + (size_t)bt * 384;
    sHdc[wv][lane] = pr[320 + lane];
    __syncthreads();

    int j = lane & 31;
    float s_t, c_t;
    sincosf(rope_angle(t, j), &s_t, &c_t);

#pragma unroll
    for (int r = 0; r < 4; ++r) {
        float qv = pr[r * 64 + lane];
        float ss = wave_sum64(qv * qv);
        float sc = rsqrtf(ss * (1.0f / 64.0f) + 1e-6f);
        float qq = qv * sc * g_q[r * 64 + lane];
        float prt = __shfl_xor(qq, 32, 64);
        float o = (lane < 32) ? fmaf(qq, c_t, -prt * s_t)
                              : fmaf(prt, s_t, qq * c_t);
        Qr[(size_t)bt * 256 + r * 64 + lane] = o;
    }
    {
        float kvv = pr[256 + lane];
        float ss = wave_sum64(kvv * kvv);
        float sc = rsqrtf(ss * (1.0f / 64.0f) + 1e-6f);
        float kk = kvv * sc * g_k[lane];
        float vv = kvv * sc * g_v[lane];
        int pos = TC + t;
        float s_p, c_p;
        sincosf(rope_angle(pos, j), &s_p, &c_p);
        float pk = __shfl_xor(kk, 32, 64);
        float pv = __shfl_xor(vv, 32, 64);
        float ko = (lane < 32) ? fmaf(kk, c_p, -pk * s_p) : fmaf(pk, s_p, kk * c_p);
        float vo = (lane < 32) ? fmaf(vv, c_p, -pv * s_p) : fmaf(pv, s_p, vv * c_p);
        size_t off = ((size_t)b * KV_LEN + pos) * 64 + lane;
        Kbuf[off] = ko;
        Vbuf[off] = vo;
    }
    {
        float a0 = 0.f, a1 = 0.f;
#pragma unroll 8
        for (int jj = 0; jj < 64; ++jj) {
            float hv = sHdc[wv][jj];
            a0 = fmaf(hv, sWI[jj * 128 + lane], a0);
            a1 = fmaf(hv, sWI[jj * 128 + 64 + lane], a1);
        }
        QI[(size_t)bt * 128 + lane] = a0;
        QI[(size_t)bt * 128 + 64 + lane] = a1;
        if (lane < 4) {
            float aw = 0.f;
            for (int jj = 0; jj < 64; ++jj)
                aw = fmaf(sHdc[wv][jj], sWw[jj * 4 + lane], aw);
            Wiw[(size_t)bt * 4 + lane] = aw;
        }
    }
}

// ---------------------------------------------------------------------------
// K2b: compress epilogue — sum 4 K-split partials, RMS/RoPE -> Kb/Vb, KI.
// ---------------------------------------------------------------------------
__global__ __launch_bounds__(256) void k_epi_comp(
    const float* __restrict__ Prec_part, const float* __restrict__ g_k,
    const float* __restrict__ g_v,
    float* __restrict__ KIbuf, float* __restrict__ Kbuf, float* __restrict__ Vbuf)
{
    int tid = threadIdx.x;
    int wv = tid >> 6;
    int lane = tid & 63;
    int sg = blockIdx.x * 4 + wv;
    int b = sg >> 9;
    int s = sg & 511;

    const float* p0 = Prec_part + (size_t)sg * 96;
    float kvv = p0[lane] + p0[98304 + lane] + p0[2 * 98304 + lane] + p0[3 * 98304 + lane];

    float ss = wave_sum64(kvv * kvv);
    float sc = rsqrtf(ss * (1.0f / 64.0f) + 1e-6f);
    float kk = kvv * sc * g_k[lane];
    float vv = kvv * sc * g_v[lane];
    int j = lane & 31;
    float sa, ca;
    sincosf(rope_angle(s, j), &sa, &ca);
    float pk = __shfl_xor(kk, 32, 64);
    float pv = __shfl_xor(vv, 32, 64);
    float ko = (lane < 32) ? fmaf(kk, ca, -pk * sa) : fmaf(pk, sa, kk * ca);
    float vo = (lane < 32) ? fmaf(vv, ca, -pv * sa) : fmaf(pv, sa, vv * ca);
    size_t off = ((size_t)b * KV_LEN + s) * 64 + lane;
    Kbuf[off] = ko;
    Vbuf[off] = vo;

    if (lane < 32) {
        float a = p0[64 + lane] + p0[98304 + 64 + lane] +
                  p0[2 * 98304 + 64 + lane] + p0[3 * 98304 + 64 + lane];
        KIbuf[((size_t)b * TC + s) * 32 + lane] = a;
    }
}

// ---------------------------------------------------------------------------
// K3: index scores + exact top-8 (unchanged, verified).
// ---------------------------------------------------------------------------
__global__ __launch_bounds__(256) void k_score_topk(
    const float* __restrict__ QI, const float* __restrict__ Wiw,
    const float* __restrict__ KIbuf, int* __restrict__ topk)
{
    int tid = threadIdx.x;
    int wv = tid >> 6;
    int lane = tid & 63;
    int bt0 = blockIdx.x * 4;
    int bt = bt0 + wv;
    int b = bt >> 11;
    int t = bt & 2047;

    __shared__ float sQ[4][128];
    __shared__ float sw[4][4];
    __shared__ float sKI[64 * 33];

    sQ[wv][lane] = QI[(size_t)bt * 128 + lane];
    sQ[wv][64 + lane] = QI[(size_t)bt * 128 + 64 + lane];
    if (lane < 4) sw[wv][lane] = Wiw[(size_t)bt * 4 + lane];

    const float* KIb = KIbuf + (size_t)b * TC * 32;
    int smax = t >> 2;
    int smax_blk = ((bt0 + 3) & 2047) >> 2;

    float vals[8];
#pragma unroll
    for (int r = 0; r < 8; ++r) vals[r] = -INFINITY;

    for (int r = 0; r < 8; ++r) {
        if (r * 64 > smax_blk) break;
        __syncthreads();
        for (int i = tid; i < 512; i += 256) {
            int row = i >> 3;
            int cseg = (i & 7) * 4;
            float4 v = *(const float4*)(KIb + (size_t)(r * 64 + row) * 32 + cseg);
            float* dst = &sKI[row * 33 + cseg];
            dst[0] = v.x; dst[1] = v.y; dst[2] = v.z; dst[3] = v.w;
        }
        __syncthreads();

        int s = r * 64 + lane;
        if (s <= smax) {
            float dd0 = 0.f, dd1 = 0.f, dd2 = 0.f, dd3 = 0.f;
#pragma unroll
            for (int c = 0; c < 32; ++c) {
                float kv = sKI[lane * 33 + c];
                dd0 = fmaf(sQ[wv][c], kv, dd0);
                dd1 = fmaf(sQ[wv][32 + c], kv, dd1);
                dd2 = fmaf(sQ[wv][64 + c], kv, dd2);
                dd3 = fmaf(sQ[wv][96 + c], kv, dd3);
            }
            vals[r] = sw[wv][0] * fmaxf(dd0, 0.f) + sw[wv][1] * fmaxf(dd1, 0.f) +
                      sw[wv][2] * fmaxf(dd2, 0.f) + sw[wv][3] * fmaxf(dd3, 0.f);
        }
    }

    unsigned consumed = 0u;
    for (int k2 = 0; k2 < 8; ++k2) {
        float bv = -INFINITY;
        int bi = 0x7fffffff;
#pragma unroll
        for (int r = 0; r < 8; ++r) {
            if (!(consumed & (1u << r))) {
                int s = lane + 64 * r;
                float v = vals[r];
                if (v > bv || (v == bv && s < bi)) { bv = v; bi = s; }
            }
        }
#pragma unroll
        for (int off = 1; off < 64; off <<= 1) {
            float ov = __shfl_xor(bv, off, 64);
            int oi = __shfl_xor(bi, off, 64);
            if (ov > bv || (ov == bv && oi < bi)) { bv = ov; bi = oi; }
        }
        if ((bi & 63) == lane) consumed |= 1u << (bi >> 6);
        if (lane == 0) topk[(size_t)bt * 8 + k2] = bi;
    }
}

// ---------------------------------------------------------------------------
// K4: sparse attention + gates + out (unchanged, verified).
// ---------------------------------------------------------------------------
__global__ __launch_bounds__(1024) void k_attn_out(
    const float* __restrict__ Qr, const float* __restrict__ Kbuf,
    const float* __restrict__ Vbuf, const int* __restrict__ topk,
    const float* __restrict__ Wg0, const float* __restrict__ bg0,
    const float* __restrict__ Wg1, const float* __restrict__ bg1,
    const float* __restrict__ Wout, const float* __restrict__ bout,
    float* __restrict__ out)
{
    int tid = threadIdx.x;
    int lt = tid >> 8;
    int t256 = tid & 255;
    int h = t256 >> 6;
    int lane = tid & 63;
    int bt = blockIdx.x * 4 + lt;
    int b = bt >> 11;
    int t = bt & 2047;

    __shared__ float sKV[4][48 * 65];
    __shared__ float sQ[4][256];
    __shared__ int sPos[4][24];
    __shared__ float sP[4][4][24];
    __shared__ float sO[4][256];
    __shared__ float sPall[4][128];

    sQ[lt][t256] = Qr[(size_t)bt * 256 + t256];
    if (t256 < 8) {
        sPos[lt][t256] = topk[(size_t)bt * 8 + t256];
    } else if (t256 < 24) {
        int rel = t256 - 8;
        int sp = t - rel;
        sPos[lt][t256] = (sp >= 0) ? (TC + sp) : -1;
    }
    __syncthreads();

    for (int i = t256; i < 768; i += 256) {
        int row = i >> 4;
        int seg = (i & 15) << 2;
        int key = (row < 24) ? row : row - 24;
        int pos = sPos[lt][key];
        if (pos >= 0) {
            const float* src = ((row < 24) ? Kbuf : Vbuf) +
                               ((size_t)b * KV_LEN + pos) * 64 + seg;
            float4 v = *(const float4*)src;
            float* dst = &sKV[lt][row * 65 + seg];
            dst[0] = v.x; dst[1] = v.y; dst[2] = v.z; dst[3] = v.w;
        }
    }
    __syncthreads();

    float scv = -INFINITY;
    if (lane < 24) {
        int pos = sPos[lt][lane];
        if (pos >= 0) {
            float dd = 0.f;
#pragma unroll
            for (int c = 0; c < 64; ++c)
                dd = fmaf(sQ[lt][h * 64 + c], sKV[lt][lane * 65 + c], dd);
            scv = dd * 0.125f;
        }
    }
    float m = scv;
#pragma unroll
    for (int off = 1; off < 64; off <<= 1) m = fmaxf(m, __shfl_xor(m, off, 64));
    float p = expf(scv - m);
    if (scv == -INFINITY) p = 0.f;
    float l = p;
#pragma unroll
    for (int off = 1; off < 64; off <<= 1) l += __shfl_xor(l, off, 64);
    p /= l;
    if (lane < 24) sP[lt][h][lane] = p;

    float o = 0.f;
#pragma unroll
    for (int j2 = 0; j2 < 24; ++j2) {
        int pos = sPos[lt][j2];
        if (pos >= 0)
            o = fmaf(sP[lt][h][j2], sKV[lt][(24 + j2) * 65 + lane], o);
    }

    int j = lane & 31;
    float sa, ca;
    sincosf(rope_angle(t, j), &sa, &ca);
    float prt = __shfl_xor(o, 32, 64);
    float oo = (lane < 32) ? fmaf(o, ca, prt * sa) : fmaf(-prt, sa, o * ca);
    sO[lt][h * 64 + lane] = oo;
    __syncthreads();

    if (t256 < 128) {
        float a;
        if (t256 < 64) {
            a = bg0[t256];
            for (int c = 0; c < 128; ++c) a = fmaf(sO[lt][c], Wg0[c * 64 + t256], a);
        } else {
            int i = t256 - 64;
            a = bg1[i];
            for (int c = 0; c < 128; ++c) a = fmaf(sO[lt][128 + c], Wg1[c * 64 + i], a);
        }
        sPall[lt][t256] = a;
    }
    __syncthreads();

    float a = bout[t256];
    for (int i = 0; i < 128; ++i) a = fmaf(sPall[lt][i], Wout[i * 256 + t256], a);
    out[(size_t)bt * 256 + t256] = a;
}

// ---------------------------------------------------------------------------
extern "C" void kernel_launch(void* const* d_in, const int* in_sizes, int n_in,
                              void* d_out, int out_size, void* d_ws, size_t ws_size,
                              hipStream_t stream) {
    const float* H       = (const float*)d_in[0];
    const float* Wc_comp = (const float*)d_in[1];
    const float* Wc_idx  = (const float*)d_in[2];
    const float* W_DQ    = (const float*)d_in[3];
    const float* W_IUQ   = (const float*)d_in[4];
    const float* W_w     = (const float*)d_in[5];
    const float* W_Q     = (const float*)d_in[6];
    const float* W_KV    = (const float*)d_in[7];
    const float* g_q     = (const float*)d_in[8];
    const float* g_k     = (const float*)d_in[9];
    const float* g_v     = (const float*)d_in[10];
    const float* Wg0     = (const float*)d_in[11];
    const float* bg0     = (const float*)d_in[12];
    const float* Wg1     = (const float*)d_in[13];
    const float* bg1     = (const float*)d_in[14];
    const float* Wout    = (const float*)d_in[15];
    const float* bout    = (const float*)d_in[16];

    float* ws  = (float*)d_ws;
    float* QI   = ws;                     // 524288
    float* Qr   = ws + 524288;            // 1048576
    float* Wiw  = ws + 1572864;           // 16384
    float* KI   = ws + 1589248;           // 32768
    float* Kb   = ws + 1622016;           // 327680
    float* Vb   = ws + 1949696;           // 327680
    int*   topkb = (int*)(ws + 2277376);  // 32768
    float* Pre  = ws + 2310144;           // 4096*384 = 1572864
    float* Prec = ws + 3883008;           // 4*1024*96 = 393216
    ush* Ap = (ush*)(ws + 4276224);       // 256*16*512  = 2097152 ush (1048576 f)
    ush* Ac = (ush*)(ws + 5324800);       // 64*128*512  = 4194304 ush (2097152 f)
    ush* Bp = (ush*)(ws + 7421952);       // 24*16*512   = 196608 ush (98304 f)
    ush* Bc = (ush*)(ws + 7520256);       // 6*128*512   = 393216 ush (196608 f)

    float* outp = (float*)d_out;

    hipLaunchKernelGGL(k_prep, dim3(3360), dim3(256), 0, stream,
                       H, W_Q, W_KV, W_DQ, Wc_comp, Wc_idx, Ap, Ac, Bp, Bc);
    hipLaunchKernelGGL(k_mfma, dim3(640), dim3(64), 0, stream,
                       Ap, Ac, Bp, Bc, Pre, Prec);
    hipLaunchKernelGGL(k_epi_proj, dim3(1024), dim3(256), 0, stream,
                       Pre, W_IUQ, W_w, g_q, g_k, g_v, QI, Wiw, Qr, Kb, Vb);
    hipLaunchKernelGGL(k_epi_comp, dim3(256), dim3(256), 0, stream,
                       Prec, g_k, g_v, KI, Kb, Vb);
    hipLaunchKernelGGL(k_score_topk, dim3((B_DIM * T_DIM) / 4), dim3(256), 0, stream,
                       QI, Wiw, KI, topkb);
    hipLaunchKernelGGL(k_attn_out, dim3((B_DIM * T_DIM) / 4), dim3(1024), 0, stream,
                       Qr, Kb, Vb, topkb, Wg0, bg0, Wg1, bg1, Wout, bout, outp);
}

// Round 7
// 182.464 us; speedup vs baseline: 1.2644x; 1.0583x over previous
//
#include <hip/hip_runtime.h>
#include <hip/hip_bf16.h>
#include <math.h>

#define T_DIM 2048
#define B_DIM 2
#define D_DIM 256
#define TC 512
#define KV_LEN 2560   // TC + T

typedef __attribute__((ext_vector_type(8))) short bf16x8;
typedef __attribute__((ext_vector_type(4))) float f32x4;
typedef unsigned short ush;

__device__ __forceinline__ float wave_sum64(float v) {
#pragma unroll
    for (int off = 32; off > 0; off >>= 1) v += __shfl_xor(v, off, 64);
    return v;
}

__device__ __forceinline__ float rope_angle(int pos, int j) {
    float inv = powf(10000.0f, -(float)j * (1.0f / 32.0f));
    return (float)pos * inv;
}

// ---------------------------------------------------------------------------
// K0: prep — fragment-linear bf16 hi/lo tiles + folded output weights.
// Regions (gid): [0,262144) Ap | [262144,786432) Ac | [786432,811008) Bp |
// [811008,860160) Bc | [860160,925696) Wcomb->Bo | [925696,925952) biascomb.
// Wcomb[k][n] = (k<128) ? Wg0[k]·Wout[0:64][n] : Wg1[k-128]·Wout[64:128][n].
// ---------------------------------------------------------------------------
__global__ __launch_bounds__(256) void k_prep(
    const float* __restrict__ H, const float* __restrict__ W_Q,
    const float* __restrict__ W_KV, const float* __restrict__ W_DQ,
    const float* __restrict__ Wc_comp, const float* __restrict__ Wc_idx,
    const float* __restrict__ Wg0, const float* __restrict__ bg0,
    const float* __restrict__ Wg1, const float* __restrict__ bg1,
    const float* __restrict__ Wout, const float* __restrict__ bout,
    ush* __restrict__ Ap, ush* __restrict__ Ac,
    ush* __restrict__ Bp, ush* __restrict__ Bc,
    ush* __restrict__ Bo, float* __restrict__ biascomb)
{
    int gid = blockIdx.x * 256 + threadIdx.x;
    float vals[8];
    ush* dst;
    bool lo_part;

    if (gid < 262144) {
        // ---- Ap ----
        int tile = gid >> 10;
        int c = (gid >> 6) & 15;
        int l = gid & 63;
        int bt = tile * 16 + (l & 15);
        int kb = (c & 7) * 32 + (l >> 4) * 8;
        const float* src = H + (size_t)bt * 256 + kb;
#pragma unroll
        for (int j = 0; j < 8; ++j) vals[j] = src[j];
        lo_part = (c >= 8);
        dst = Ap + (size_t)gid * 8;
    } else if (gid < 786432) {
        // ---- Ac ----
        int g = gid - 262144;
        int tile = g >> 13;
        int c = (g >> 6) & 127;
        int l = g & 63;
        int m = tile * 16 + (l & 15);
        int s = m & 511;
        int b = m >> 9;
        int k2b = (c & 63) * 32 + (l >> 4) * 8;
        int r4 = 4 * s + (k2b >> 8);
        int col = k2b & 255;
        if (r4 < T_DIM) {
            const float* src = H + ((size_t)b * T_DIM + r4) * 256 + col;
#pragma unroll
            for (int j = 0; j < 8; ++j) vals[j] = src[j];
        } else {
#pragma unroll
            for (int j = 0; j < 8; ++j) vals[j] = 0.f;
        }
        lo_part = (c >= 64);
        dst = Ac + (size_t)g * 8;
    } else if (gid < 811008) {
        // ---- Bp ----
        int g = gid - 786432;
        int tile = g >> 10;
        int c = (g >> 6) & 15;
        int l = g & 63;
        int n = tile * 16 + (l & 15);
        int kb = (c & 7) * 32 + (l >> 4) * 8;
#pragma unroll
        for (int j = 0; j < 8; ++j) {
            int k = kb + j;
            float w;
            if (n < 256)      w = W_Q[(size_t)k * 256 + n];
            else if (n < 320) w = W_KV[(size_t)k * 64 + (n - 256)];
            else              w = W_DQ[(size_t)k * 64 + (n - 320)];
            vals[j] = w;
        }
        lo_part = (c >= 8);
        dst = Bp + (size_t)g * 8;
    } else if (gid < 860160) {
        // ---- Bc ----
        int g = gid - 811008;
        int tile = g >> 13;
        int c = (g >> 6) & 127;
        int l = g & 63;
        int n = tile * 16 + (l & 15);
        int k2b = (c & 63) * 32 + (l >> 4) * 8;
#pragma unroll
        for (int j = 0; j < 8; ++j) {
            int k = k2b + j;
            vals[j] = (n < 64) ? Wc_comp[(size_t)k * 64 + n]
                               : Wc_idx[(size_t)k * 32 + (n - 64)];
        }
        lo_part = (c >= 64);
        dst = Bc + (size_t)g * 8;
    } else if (gid < 925696) {
        // ---- Wcomb -> Bo (fragment scatter) ----
        int g = gid - 860160;
        int k = g >> 8;
        int n = g & 255;
        float acc = 0.f;
        if (k < 128) {
            for (int i = 0; i < 64; ++i)
                acc = fmaf(Wg0[k * 64 + i], Wout[(size_t)i * 256 + n], acc);
        } else {
            for (int i = 0; i < 64; ++i)
                acc = fmaf(Wg1[(k - 128) * 64 + i], Wout[(size_t)(64 + i) * 256 + n], acc);
        }
        __hip_bfloat16 hb = __float2bfloat16(acc);
        float hif = __bfloat162float(hb);
        __hip_bfloat16 lb = __float2bfloat16(acc - hif);
        int tile = n >> 4;
        int chi = k >> 5;
        int lane2 = (n & 15) + 16 * ((k >> 3) & 3);
        int j = k & 7;
        Bo[(size_t)(tile * 16 + chi) * 512 + lane2 * 8 + j] = *(ush*)&hb;
        Bo[(size_t)(tile * 16 + chi + 8) * 512 + lane2 * 8 + j] = *(ush*)&lb;
        return;
    } else if (gid < 925952) {
        int n = gid - 925696;
        float acc = bout[n];
        for (int i = 0; i < 64; ++i) {
            acc = fmaf(bg0[i], Wout[(size_t)i * 256 + n], acc);
            acc = fmaf(bg1[i], Wout[(size_t)(64 + i) * 256 + n], acc);
        }
        biascomb[n] = acc;
        return;
    } else {
        return;
    }

    bf16x8 out8;
#pragma unroll
    for (int j = 0; j < 8; ++j) {
        float x = vals[j];
        __hip_bfloat16 hb = __float2bfloat16(x);
        if (!lo_part) {
            out8[j] = *(short*)&hb;
        } else {
            float hif = __bfloat162float(hb);
            __hip_bfloat16 lb = __float2bfloat16(x - hif);
            out8[j] = *(short*)&lb;
        }
    }
    *(bf16x8*)dst = out8;
}

// ---------------------------------------------------------------------------
// K1: MFMA GEMMs (proj + compress), verified R6 structure.
// ---------------------------------------------------------------------------
__global__ __launch_bounds__(64) void k_mfma(
    const ush* __restrict__ Ap, const ush* __restrict__ Ac,
    const ush* __restrict__ Bp, const ush* __restrict__ Bc,
    float* __restrict__ Pre, float* __restrict__ Prec_part)
{
    int lane = threadIdx.x;
    int mrow = lane & 15;
    int q = lane >> 4;

    f32x4 acc[2][6];
#pragma unroll
    for (int mt = 0; mt < 2; ++mt)
#pragma unroll
        for (int nt = 0; nt < 6; ++nt) acc[mt][nt] = (f32x4){0.f, 0.f, 0.f, 0.f};

    if (blockIdx.x < 512) {
        int p = blockIdx.x;
        int m0 = (p >> 2) * 32;
        int n0 = (p & 3) * 96;
        int at0 = (m0 >> 4) * 16;
        int bt0n = (n0 >> 4) * 16;

        for (int c = 0; c < 8; ++c) {
            bf16x8 ahi[2], alo[2], bhi[6], blo[6];
#pragma unroll
            for (int mt = 0; mt < 2; ++mt) {
                ahi[mt] = *(const bf16x8*)(Ap + (size_t)((at0 + mt * 16) + c) * 512 + lane * 8);
                alo[mt] = *(const bf16x8*)(Ap + (size_t)((at0 + mt * 16) + 8 + c) * 512 + lane * 8);
            }
#pragma unroll
            for (int nt = 0; nt < 6; ++nt) {
                bhi[nt] = *(const bf16x8*)(Bp + (size_t)((bt0n + nt * 16) + c) * 512 + lane * 8);
                blo[nt] = *(const bf16x8*)(Bp + (size_t)((bt0n + nt * 16) + 8 + c) * 512 + lane * 8);
            }
#pragma unroll
            for (int mt = 0; mt < 2; ++mt)
#pragma unroll
                for (int nt = 0; nt < 6; ++nt) {
                    acc[mt][nt] = __builtin_amdgcn_mfma_f32_16x16x32_bf16(ahi[mt], bhi[nt], acc[mt][nt], 0, 0, 0);
                    acc[mt][nt] = __builtin_amdgcn_mfma_f32_16x16x32_bf16(ahi[mt], blo[nt], acc[mt][nt], 0, 0, 0);
                    acc[mt][nt] = __builtin_amdgcn_mfma_f32_16x16x32_bf16(alo[mt], bhi[nt], acc[mt][nt], 0, 0, 0);
                }
        }

#pragma unroll
        for (int mt = 0; mt < 2; ++mt)
#pragma unroll
            for (int nt = 0; nt < 6; ++nt)
#pragma unroll
                for (int reg = 0; reg < 4; ++reg)
                    Pre[(size_t)(m0 + 16 * mt + 4 * q + reg) * 384 + n0 + 16 * nt + mrow] =
                        acc[mt][nt][reg];
    } else {
        int cb = blockIdx.x - 512;
        int m0 = (cb >> 2) * 32;
        int q4 = cb & 3;
        int at0 = (m0 >> 4) * 128;

        for (int cl = 0; cl < 16; ++cl) {
            int c = q4 * 16 + cl;
            bf16x8 ahi[2], alo[2], bhi[6], blo[6];
#pragma unroll
            for (int mt = 0; mt < 2; ++mt) {
                ahi[mt] = *(const bf16x8*)(Ac + (size_t)((at0 + mt * 128) + c) * 512 + lane * 8);
                alo[mt] = *(const bf16x8*)(Ac + (size_t)((at0 + mt * 128) + 64 + c) * 512 + lane * 8);
            }
#pragma unroll
            for (int nt = 0; nt < 6; ++nt) {
                bhi[nt] = *(const bf16x8*)(Bc + (size_t)(nt * 128 + c) * 512 + lane * 8);
                blo[nt] = *(const bf16x8*)(Bc + (size_t)(nt * 128 + 64 + c) * 512 + lane * 8);
            }
#pragma unroll
            for (int mt = 0; mt < 2; ++mt)
#pragma unroll
                for (int nt = 0; nt < 6; ++nt) {
                    acc[mt][nt] = __builtin_amdgcn_mfma_f32_16x16x32_bf16(ahi[mt], bhi[nt], acc[mt][nt], 0, 0, 0);
                    acc[mt][nt] = __builtin_amdgcn_mfma_f32_16x16x32_bf16(ahi[mt], blo[nt], acc[mt][nt], 0, 0, 0);
                    acc[mt][nt] = __builtin_amdgcn_mfma_f32_16x16x32_bf16(alo[mt], bhi[nt], acc[mt][nt], 0, 0, 0);
                }
        }

        float* dst = Prec_part + (size_t)q4 * (1024 * 96);
#pragma unroll
        for (int mt = 0; mt < 2; ++mt)
#pragma unroll
            for (int nt = 0; nt < 6; ++nt)
#pragma unroll
                for (int reg = 0; reg < 4; ++reg)
                    dst[(size_t)(m0 + 16 * mt + 4 * q + reg) * 96 + 16 * nt + mrow] =
                        acc[mt][nt][reg];
    }
}

// ---------------------------------------------------------------------------
// K2: merged epilogues. blocks [0,1024) = proj epi; [1024,1280) = comp epi.
// ---------------------------------------------------------------------------
__global__ __launch_bounds__(256) void k_epi(
    const float* __restrict__ Pre, const float* __restrict__ Prec_part,
    const float* __restrict__ W_IUQ, const float* __restrict__ W_w,
    const float* __restrict__ g_q, const float* __restrict__ g_k,
    const float* __restrict__ g_v,
    float* __restrict__ QI, float* __restrict__ Wiw, float* __restrict__ Qr,
    float* __restrict__ KIbuf, float* __restrict__ Kbuf, float* __restrict__ Vbuf)
{
    __shared__ float sWI[8192];
    __shared__ float sWw[256];
    __shared__ float sHdc[4][64];

    int tid = threadIdx.x;
    int wv = tid >> 6;
    int lane = tid & 63;

    if (blockIdx.x < 1024) {
        int bt = blockIdx.x * 4 + wv;
        int b = bt >> 11;
        int t = bt & 2047;

        for (int i = tid * 4; i < 8192; i += 1024)
            *(float4*)&sWI[i] = *(const float4*)(W_IUQ + i);
        if (tid < 64) ((float4*)sWw)[tid] = ((const float4*)W_w)[tid];

        const float* pr = Pre + (size_t)bt * 384;
        sHdc[wv][lane] = pr[320 + lane];
        __syncthreads();

        int j = lane & 31;
        float s_t, c_t;
        sincosf(rope_angle(t, j), &s_t, &c_t);

#pragma unroll
        for (int r = 0; r < 4; ++r) {
            float qv = pr[r * 64 + lane];
            float ss = wave_sum64(qv * qv);
            float sc = rsqrtf(ss * (1.0f / 64.0f) + 1e-6f);
            float qq = qv * sc * g_q[r * 64 + lane];
            float prt = __shfl_xor(qq, 32, 64);
            float o = (lane < 32) ? fmaf(qq, c_t, -prt * s_t)
                                  : fmaf(prt, s_t, qq * c_t);
            Qr[(size_t)bt * 256 + r * 64 + lane] = o;
        }
        {
            float kvv = pr[256 + lane];
            float ss = wave_sum64(kvv * kvv);
            float sc = rsqrtf(ss * (1.0f / 64.0f) + 1e-6f);
            float kk = kvv * sc * g_k[lane];
            float vv = kvv * sc * g_v[lane];
            int pos = TC + t;
            float s_p, c_p;
            sincosf(rope_angle(pos, j), &s_p, &c_p);
            float pk = __shfl_xor(kk, 32, 64);
            float pv = __shfl_xor(vv, 32, 64);
            float ko = (lane < 32) ? fmaf(kk, c_p, -pk * s_p) : fmaf(pk, s_p, kk * c_p);
            float vo = (lane < 32) ? fmaf(vv, c_p, -pv * s_p) : fmaf(pv, s_p, vv * c_p);
            size_t off = ((size_t)b * KV_LEN + pos) * 64 + lane;
            Kbuf[off] = ko;
            Vbuf[off] = vo;
        }
        {
            float a0 = 0.f, a1 = 0.f;
#pragma unroll 8
            for (int jj = 0; jj < 64; ++jj) {
                float hv = sHdc[wv][jj];
                a0 = fmaf(hv, sWI[jj * 128 + lane], a0);
                a1 = fmaf(hv, sWI[jj * 128 + 64 + lane], a1);
            }
            QI[(size_t)bt * 128 + lane] = a0;
            QI[(size_t)bt * 128 + 64 + lane] = a1;
            if (lane < 4) {
                float aw = 0.f;
                for (int jj = 0; jj < 64; ++jj)
                    aw = fmaf(sHdc[wv][jj], sWw[jj * 4 + lane], aw);
                Wiw[(size_t)bt * 4 + lane] = aw;
            }
        }
    } else {
        int sg = (blockIdx.x - 1024) * 4 + wv;
        int b = sg >> 9;
        int s = sg & 511;

        const float* p0 = Prec_part + (size_t)sg * 96;
        float kvv = p0[lane] + p0[98304 + lane] + p0[2 * 98304 + lane] + p0[3 * 98304 + lane];

        float ss = wave_sum64(kvv * kvv);
        float sc = rsqrtf(ss * (1.0f / 64.0f) + 1e-6f);
        float kk = kvv * sc * g_k[lane];
        float vv = kvv * sc * g_v[lane];
        int j = lane & 31;
        float sa, ca;
        sincosf(rope_angle(s, j), &sa, &ca);
        float pk = __shfl_xor(kk, 32, 64);
        float pv = __shfl_xor(vv, 32, 64);
        float ko = (lane < 32) ? fmaf(kk, ca, -pk * sa) : fmaf(pk, sa, kk * ca);
        float vo = (lane < 32) ? fmaf(vv, ca, -pv * sa) : fmaf(pv, sa, vv * ca);
        size_t off = ((size_t)b * KV_LEN + s) * 64 + lane;
        Kbuf[off] = ko;
        Vbuf[off] = vo;

        if (lane < 32) {
            float a = p0[64 + lane] + p0[98304 + 64 + lane] +
                      p0[2 * 98304 + 64 + lane] + p0[3 * 98304 + 64 + lane];
            KIbuf[((size_t)b * TC + s) * 32 + lane] = a;
        }
    }
}

// ---------------------------------------------------------------------------
// K3: index scores + exact top-8 (unchanged, verified).
// ---------------------------------------------------------------------------
__global__ __launch_bounds__(256) void k_score_topk(
    const float* __restrict__ QI, const float* __restrict__ Wiw,
    const float* __restrict__ KIbuf, int* __restrict__ topk)
{
    int tid = threadIdx.x;
    int wv = tid >> 6;
    int lane = tid & 63;
    int bt0 = blockIdx.x * 4;
    int bt = bt0 + wv;
    int b = bt >> 11;
    int t = bt & 2047;

    __shared__ float sQ[4][128];
    __shared__ float sw[4][4];
    __shared__ float sKI[64 * 33];

    sQ[wv][lane] = QI[(size_t)bt * 128 + lane];
    sQ[wv][64 + lane] = QI[(size_t)bt * 128 + 64 + lane];
    if (lane < 4) sw[wv][lane] = Wiw[(size_t)bt * 4 + lane];

    const float* KIb = KIbuf + (size_t)b * TC * 32;
    int smax = t >> 2;
    int smax_blk = ((bt0 + 3) & 2047) >> 2;

    float vals[8];
#pragma unroll
    for (int r = 0; r < 8; ++r) vals[r] = -INFINITY;

    for (int r = 0; r < 8; ++r) {
        if (r * 64 > smax_blk) break;
        __syncthreads();
        for (int i = tid; i < 512; i += 256) {
            int row = i >> 3;
            int cseg = (i & 7) * 4;
            float4 v = *(const float4*)(KIb + (size_t)(r * 64 + row) * 32 + cseg);
            float* dst = &sKI[row * 33 + cseg];
            dst[0] = v.x; dst[1] = v.y; dst[2] = v.z; dst[3] = v.w;
        }
        __syncthreads();

        int s = r * 64 + lane;
        if (s <= smax) {
            float dd0 = 0.f, dd1 = 0.f, dd2 = 0.f, dd3 = 0.f;
#pragma unroll
            for (int c = 0; c < 32; ++c) {
                float kv = sKI[lane * 33 + c];
                dd0 = fmaf(sQ[wv][c], kv, dd0);
                dd1 = fmaf(sQ[wv][32 + c], kv, dd1);
                dd2 = fmaf(sQ[wv][64 + c], kv, dd2);
                dd3 = fmaf(sQ[wv][96 + c], kv, dd3);
            }
            vals[r] = sw[wv][0] * fmaxf(dd0, 0.f) + sw[wv][1] * fmaxf(dd1, 0.f) +
                      sw[wv][2] * fmaxf(dd2, 0.f) + sw[wv][3] * fmaxf(dd3, 0.f);
        }
    }

    unsigned consumed = 0u;
    for (int k2 = 0; k2 < 8; ++k2) {
        float bv = -INFINITY;
        int bi = 0x7fffffff;
#pragma unroll
        for (int r = 0; r < 8; ++r) {
            if (!(consumed & (1u << r))) {
                int s = lane + 64 * r;
                float v = vals[r];
                if (v > bv || (v == bv && s < bi)) { bv = v; bi = s; }
            }
        }
#pragma unroll
        for (int off = 1; off < 64; off <<= 1) {
            float ov = __shfl_xor(bv, off, 64);
            int oi = __shfl_xor(bi, off, 64);
            if (ov > bv || (ov == bv && oi < bi)) { bv = ov; bi = oi; }
        }
        if ((bi & 63) == lane) consumed |= 1u << (bi >> 6);
        if (lane == 0) topk[(size_t)bt * 8 + k2] = bi;
    }
}

// ---------------------------------------------------------------------------
// K4: attention only — scores/softmax/PV/inverse-rope -> Obuf rows (fp32).
// 4 tokens/block (1024 thr, wave per head).
// ---------------------------------------------------------------------------
__global__ __launch_bounds__(1024) void k_attn(
    const float* __restrict__ Qr, const float* __restrict__ Kbuf,
    const float* __restrict__ Vbuf, const int* __restrict__ topk,
    float* __restrict__ Obuf)
{
    int tid = threadIdx.x;
    int lt = tid >> 8;
    int t256 = tid & 255;
    int h = t256 >> 6;
    int lane = tid & 63;
    int bt = blockIdx.x * 4 + lt;
    int b = bt >> 11;
    int t = bt & 2047;

    __shared__ float sKV[4][48 * 65];
    __shared__ float sQ[4][256];
    __shared__ int sPos[4][24];
    __shared__ float sP[4][4][24];

    sQ[lt][t256] = Qr[(size_t)bt * 256 + t256];
    if (t256 < 8) {
        sPos[lt][t256] = topk[(size_t)bt * 8 + t256];
    } else if (t256 < 24) {
        int rel = t256 - 8;
        int sp = t - rel;
        sPos[lt][t256] = (sp >= 0) ? (TC + sp) : -1;
    }
    __syncthreads();

    for (int i = t256; i < 768; i += 256) {
        int row = i >> 4;
        int seg = (i & 15) << 2;
        int key = (row < 24) ? row : row - 24;
        int pos = sPos[lt][key];
        if (pos >= 0) {
            const float* src = ((row < 24) ? Kbuf : Vbuf) +
                               ((size_t)b * KV_LEN + pos) * 64 + seg;
            float4 v = *(const float4*)src;
            float* dst = &sKV[lt][row * 65 + seg];
            dst[0] = v.x; dst[1] = v.y; dst[2] = v.z; dst[3] = v.w;
        }
    }
    __syncthreads();

    float scv = -INFINITY;
    if (lane < 24) {
        int pos = sPos[lt][lane];
        if (pos >= 0) {
            float dd = 0.f;
#pragma unroll
            for (int c = 0; c < 64; ++c)
                dd = fmaf(sQ[lt][h * 64 + c], sKV[lt][lane * 65 + c], dd);
            scv = dd * 0.125f;
        }
    }
    float m = scv;
#pragma unroll
    for (int off = 1; off < 64; off <<= 1) m = fmaxf(m, __shfl_xor(m, off, 64));
    float p = expf(scv - m);
    if (scv == -INFINITY) p = 0.f;
    float l = p;
#pragma unroll
    for (int off = 1; off < 64; off <<= 1) l += __shfl_xor(l, off, 64);
    p /= l;
    if (lane < 24) sP[lt][h][lane] = p;   // wave-local

    float o = 0.f;
#pragma unroll
    for (int j2 = 0; j2 < 24; ++j2) {
        int pos = sPos[lt][j2];
        if (pos >= 0)
            o = fmaf(sP[lt][h][j2], sKV[lt][(24 + j2) * 65 + lane], o);
    }

    int j = lane & 31;
    float sa, ca;
    sincosf(rope_angle(t, j), &sa, &ca);
    float prt = __shfl_xor(o, 32, 64);
    float oo = (lane < 32) ? fmaf(o, ca, prt * sa) : fmaf(-prt, sa, o * ca);
    Obuf[(size_t)bt * 256 + h * 64 + lane] = oo;
}

// ---------------------------------------------------------------------------
// K5: convert Obuf rows to A-fragment-linear bf16 hi/lo (mirror of Ap).
// ---------------------------------------------------------------------------
__global__ __launch_bounds__(256) void k_cvtO(
    const float* __restrict__ Obuf, ush* __restrict__ Ao)
{
    int gid = blockIdx.x * 256 + threadIdx.x;   // < 262144
    int tile = gid >> 10;
    int c = (gid >> 6) & 15;
    int l = gid & 63;
    int row = tile * 16 + (l & 15);
    int kb = (c & 7) * 32 + (l >> 4) * 8;
    const float* src = Obuf + (size_t)row * 256 + kb;
    bool lo_part = (c >= 8);
    bf16x8 out8;
#pragma unroll
    for (int j = 0; j < 8; ++j) {
        float x = src[j];
        __hip_bfloat16 hb = __float2bfloat16(x);
        if (!lo_part) {
            out8[j] = *(short*)&hb;
        } else {
            float hif = __bfloat162float(hb);
            __hip_bfloat16 lb = __float2bfloat16(x - hif);
            out8[j] = *(short*)&lb;
        }
    }
    *(bf16x8*)(Ao + (size_t)gid * 8) = out8;
}

// ---------------------------------------------------------------------------
// K6: output GEMM  out = O @ Wcomb + biascomb.  512 one-wave blocks,
// wave tile M=32 x N=64, hi/lo 3-product split.
// ---------------------------------------------------------------------------
__global__ __launch_bounds__(64) void k_out(
    const ush* __restrict__ Ao, const ush* __restrict__ Bo,
    const float* __restrict__ biascomb, float* __restrict__ out)
{
    int lane = threadIdx.x;
    int mrow = lane & 15;
    int q = lane >> 4;
    int p = blockIdx.x;
    int m0 = (p >> 2) * 32;
    int n0 = (p & 3) * 64;
    int at0 = (m0 >> 4) * 16;
    int bt0n = (n0 >> 4) * 16;

    f32x4 acc[2][4];
#pragma unroll
    for (int mt = 0; mt < 2; ++mt)
#pragma unroll
        for (int nt = 0; nt < 4; ++nt) acc[mt][nt] = (f32x4){0.f, 0.f, 0.f, 0.f};

    for (int c = 0; c < 8; ++c) {
        bf16x8 ahi[2], alo[2], bhi[4], blo[4];
#pragma unroll
        for (int mt = 0; mt < 2; ++mt) {
            ahi[mt] = *(const bf16x8*)(Ao + (size_t)((at0 + mt * 16) + c) * 512 + lane * 8);
            alo[mt] = *(const bf16x8*)(Ao + (size_t)((at0 + mt * 16) + 8 + c) * 512 + lane * 8);
        }
#pragma unroll
        for (int nt = 0; nt < 4; ++nt) {
            bhi[nt] = *(const bf16x8*)(Bo + (size_t)((bt0n + nt * 16) + c) * 512 + lane * 8);
            blo[nt] = *(const bf16x8*)(Bo + (size_t)((bt0n + nt * 16) + 8 + c) * 512 + lane * 8);
        }
#pragma unroll
        for (int mt = 0; mt < 2; ++mt)
#pragma unroll
            for (int nt = 0; nt < 4; ++nt) {
                acc[mt][nt] = __builtin_amdgcn_mfma_f32_16x16x32_bf16(ahi[mt], bhi[nt], acc[mt][nt], 0, 0, 0);
                acc[mt][nt] = __builtin_amdgcn_mfma_f32_16x16x32_bf16(ahi[mt], blo[nt], acc[mt][nt], 0, 0, 0);
                acc[mt][nt] = __builtin_amdgcn_mfma_f32_16x16x32_bf16(alo[mt], bhi[nt], acc[mt][nt], 0, 0, 0);
            }
    }

#pragma unroll
    for (int mt = 0; mt < 2; ++mt)
#pragma unroll
        for (int nt = 0; nt < 4; ++nt) {
            float bia = biascomb[n0 + 16 * nt + mrow];
#pragma unroll
            for (int reg = 0; reg < 4; ++reg)
                out[(size_t)(m0 + 16 * mt + 4 * q + reg) * 256 + n0 + 16 * nt + mrow] =
                    acc[mt][nt][reg] + bia;
        }
}

// ---------------------------------------------------------------------------
extern "C" void kernel_launch(void* const* d_in, const int* in_sizes, int n_in,
                              void* d_out, int out_size, void* d_ws, size_t ws_size,
                              hipStream_t stream) {
    const float* H       = (const float*)d_in[0];
    const float* Wc_comp = (const float*)d_in[1];
    const float* Wc_idx  = (const float*)d_in[2];
    const float* W_DQ    = (const float*)d_in[3];
    const float* W_IUQ   = (const float*)d_in[4];
    const float* W_w     = (const float*)d_in[5];
    const float* W_Q     = (const float*)d_in[6];
    const float* W_KV    = (const float*)d_in[7];
    const float* g_q     = (const float*)d_in[8];
    const float* g_k     = (const float*)d_in[9];
    const float* g_v     = (const float*)d_in[10];
    const float* Wg0     = (const float*)d_in[11];
    const float* bg0     = (const float*)d_in[12];
    const float* Wg1     = (const float*)d_in[13];
    const float* bg1     = (const float*)d_in[14];
    const float* Wout    = (const float*)d_in[15];
    const float* bout    = (const float*)d_in[16];

    float* ws  = (float*)d_ws;
    float* QI    = ws;                     // 524288
    float* Qr    = ws + 524288;            // 1048576
    float* Wiw   = ws + 1572864;           // 16384
    float* KI    = ws + 1589248;           // 32768
    float* Kb    = ws + 1622016;           // 327680
    float* Vb    = ws + 1949696;           // 327680
    int*   topkb = (int*)(ws + 2277376);   // 32768
    float* Pre   = ws + 2310144;           // 4096*384 = 1572864
    float* Prec  = ws + 3883008;           // 4*1024*96 = 393216
    ush* Ap = (ush*)(ws + 4276224);        // 256*16*512 ush (1048576 f)
    ush* Ac = (ush*)(ws + 5324800);        // 64*128*512 ush (2097152 f)
    ush* Bp = (ush*)(ws + 7421952);        // 24*16*512 ush (98304 f)
    ush* Bc = (ush*)(ws + 7520256);        // 6*128*512 ush (196608 f)
    ush* Bo = (ush*)(ws + 7716864);        // 16*16*512 ush (65536 f)
    float* biascomb = ws + 7782400;        // 256
    // aliases (regions dead after k_mfma):
    float* Obuf = ws + 4276224;            // 4096*256 = 1048576 f (over Ap)
    ush*   Ao   = (ush*)(ws + 5324800);    // 256*16*512 ush (over Ac)

    float* outp = (float*)d_out;

    hipLaunchKernelGGL(k_prep, dim3(3617), dim3(256), 0, stream,
                       H, W_Q, W_KV, W_DQ, Wc_comp, Wc_idx,
                       Wg0, bg0, Wg1, bg1, Wout, bout,
                       Ap, Ac, Bp, Bc, Bo, biascomb);
    hipLaunchKernelGGL(k_mfma, dim3(640), dim3(64), 0, stream,
                       Ap, Ac, Bp, Bc, Pre, Prec);
    hipLaunchKernelGGL(k_epi, dim3(1280), dim3(256), 0, stream,
                       Pre, Prec, W_IUQ, W_w, g_q, g_k, g_v,
                       QI, Wiw, Qr, KI, Kb, Vb);
    hipLaunchKernelGGL(k_score_topk, dim3((B_DIM * T_DIM) / 4), dim3(256), 0, stream,
                       QI, Wiw, KI, topkb);
    hipLaunchKernelGGL(k_attn, dim3((B_DIM * T_DIM) / 4), dim3(1024), 0, stream,
                       Qr, Kb, Vb, topkb, Obuf);
    hipLaunchKernelGGL(k_cvtO, dim3(1024), dim3(256), 0, stream,
                       Obuf, Ao);
    hipLaunchKernelGGL(k_out, dim3(512), dim3(64), 0, stream,
                       Ao, Bo, biascomb, outp);
}